// Round 12
// baseline (1253.327 us; speedup 1.0000x reference)
//
#include <hip/hip_runtime.h>
#include <hip/hip_bf16.h>

#define NN   40000
#define EE   640000
#define CAP  64        // ELL slots per (node, edge-type); P(Poisson(16) > 64) ~ 1e-19

// ---------------- tiny precompute: wa[v][k] = (W @ a_vec)[k], 8 vectors of length 128 ----------------

__global__ __launch_bounds__(256) void wa_k(const float* __restrict__ W1, const float* __restrict__ a1,
                                            const float* __restrict__ W2, const float* __restrict__ a2,
                                            float* __restrict__ wa) {
    int gid = blockIdx.x * 256 + threadIdx.x;    // 0..1023
    int v = gid >> 7, k = gid & 127;
    float s = 0.f;
    if (v < 4) {
        const float* W = W1 + (v >> 1) * 128 * 128;
        const float* a = a1 + (v >> 1) * 2 * 128 + (v & 1) * 128;
        #pragma unroll 4
        for (int c = 0; c < 128; c++) s += W[k * 128 + c] * a[c];
    } else {
        int u = v - 4;
        const float* W = W2 + (u >> 1) * 128 * 64;
        const float* a = a2 + (u >> 1) * 2 * 64 + (u & 1) * 64;
        #pragma unroll 4
        for (int c = 0; c < 64; c++) s += W[k * 64 + c] * a[c];
    }
    wa[gid] = s;
}

// ---------------- fused: GEMM (both types, bf16 out) + el/er via precomputed wa + decision MLP
//                  + (layer 1 only) ELL build, latency-split across compute phases.
// __launch_bounds__(256,4): cap VGPR<=128 — without it the phase-split schedule spills (VGPR 256,
// ~1GB scratch traffic/dispatch, round-11 regression 361->658us). ----------------

template <int M, bool BUILD>
__global__ __launch_bounds__(256, 4) void fusedgemm_k(const float* __restrict__ X,
                                                      const float* __restrict__ WA, const float* __restrict__ WB,
                                                      const float* __restrict__ wa,   // 4 vectors x 128 (layer-selected)
                                                      const float* __restrict__ dw1, const float* __restrict__ db1,
                                                      const float* __restrict__ dw2, const float* __restrict__ db2,
                                                      __hip_bfloat16* __restrict__ HbA, __hip_bfloat16* __restrict__ HbB,
                                                      float* __restrict__ elA, float* __restrict__ erA,
                                                      float* __restrict__ elB, float* __restrict__ erB,
                                                      float* __restrict__ wdec,
                                                      const int* __restrict__ eiA, const int* __restrict__ eiB,
                                                      int* __restrict__ cnt, int* __restrict__ ell) {
    constexpr int K = 128;
    constexpr int NB = 16;
    constexpr int G = 256 / M;   // 2 (M=128) or 4 (M=64)
    constexpr int R = NB / G;    // 8 or 4
    __shared__ float xs[NB][K + 4];   // row stride 132 floats = 528B, 16B-aligned
    __shared__ float hid[NB][65];
    __shared__ float lg[16][2];
    int n0 = blockIdx.x * NB;
    int tid = threadIdx.x;

    // ---- stage X tile (float4) ----
    for (int idx = tid; idx < NB * (K / 4); idx += 256) {
        int r = idx >> 5, k4 = (idx & 31) << 2;
        *(float4*)&xs[r][k4] = *(const float4*)&X[(size_t)(n0 + r) * K + k4];
    }

    // ---- BUILD phase 1: issue edge loads (latency hides under GEMM) ----
    int sA, dA, sB, dB;
    if (BUILD) {
        int gid = blockIdx.x * 256 + tid;          // grid is exactly 640000 = E threads
        sA = eiA[gid]; dA = eiA[EE + gid];
        sB = eiB[gid]; dB = NN + eiB[EE + gid];
    }
    __syncthreads();

    // ---- GEMM both types: float4 xs broadcasts ----
    const int c = tid % M;
    const int g = tid / M;
    float accA[R], accB[R];
    #pragma unroll
    for (int r = 0; r < R; r++) { accA[r] = 0.f; accB[r] = 0.f; }
    for (int k4 = 0; k4 < K; k4 += 4) {
        float4 xv[R];
        #pragma unroll
        for (int r = 0; r < R; r++) xv[r] = *(float4*)&xs[g * R + r][k4];
        #define GSTEP(comp, kk)                                              \
        {                                                                    \
            float wA = WA[(k4 + kk) * M + c];                                \
            float wB = WB[(k4 + kk) * M + c];                                \
            _Pragma("unroll")                                                \
            for (int r = 0; r < R; r++) {                                    \
                accA[r] = fmaf(xv[r].comp, wA, accA[r]);                     \
                accB[r] = fmaf(xv[r].comp, wB, accB[r]);                     \
            }                                                                \
        }
        GSTEP(x, 0) GSTEP(y, 1) GSTEP(z, 2) GSTEP(w, 3)
        #undef GSTEP
    }

    // ---- BUILD phase 2: atomics (edge data long since arrived; atomic latency hides under dec-MLP) ----
    int cA, cB;
    if (BUILD) {
        cA = atomicAdd(&cnt[dA], 1);
        cB = atomicAdd(&cnt[dB], 1);
    }

    // ---- decision MLP part 1: float4 xs reads ----
    {
        int dc = tid & 63, dg = tid >> 6;      // 4 groups x 4 rows
        float da[4] = {0.f, 0.f, 0.f, 0.f};
        for (int k4 = 0; k4 < 128; k4 += 4) {
            float4 xr[4];
            #pragma unroll
            for (int r = 0; r < 4; r++) xr[r] = *(float4*)&xs[dg * 4 + r][k4];
            float w0 = dw1[(k4 + 0) * 64 + dc];
            float w1 = dw1[(k4 + 1) * 64 + dc];
            float w2 = dw1[(k4 + 2) * 64 + dc];
            float w3 = dw1[(k4 + 3) * 64 + dc];
            #pragma unroll
            for (int r = 0; r < 4; r++) {
                float s = fmaf(xr[r].x, w0, fmaf(xr[r].y, w1, fmaf(xr[r].z, w2, xr[r].w * w3)));
                da[r] += s;
            }
        }
        float b = db1[dc];
        #pragma unroll
        for (int r = 0; r < 4; r++) hid[dg * 4 + r][dc] = fmaxf(da[r] + b, 0.f);
    }

    // ---- BUILD phase 3: ELL stores (fire-and-forget) ----
    if (BUILD) {
        if (cA < CAP) ell[((size_t)dA << 6) + cA] = sA;
        if (cB < CAP) ell[((size_t)dB << 6) + cB] = sB;
    }

    // ---- el/er from precomputed wa vectors: row-dot over xs (no LDS scratch, no barriers) ----
    {
        int row = tid >> 4, lane16 = tid & 15;
        float s0 = 0.f, s1 = 0.f, s2 = 0.f, s3 = 0.f;
        #pragma unroll
        for (int kk = 0; kk < 8; kk++) {
            int k = lane16 + kk * 16;
            float xv = xs[row][k];
            s0 = fmaf(xv, wa[0 * 128 + k], s0);
            s1 = fmaf(xv, wa[1 * 128 + k], s1);
            s2 = fmaf(xv, wa[2 * 128 + k], s2);
            s3 = fmaf(xv, wa[3 * 128 + k], s3);
        }
        #pragma unroll
        for (int o = 8; o > 0; o >>= 1) {
            s0 += __shfl_down(s0, o, 16);
            s1 += __shfl_down(s1, o, 16);
            s2 += __shfl_down(s2, o, 16);
            s3 += __shfl_down(s3, o, 16);
        }
        if (lane16 == 0) {
            elA[n0 + row] = s0; erA[n0 + row] = s1;
            elB[n0 + row] = s2; erB[n0 + row] = s3;
        }
    }

    // ---- bf16 H stores ----
    #pragma unroll
    for (int r = 0; r < R; r++) {
        HbA[(size_t)(n0 + g * R + r) * M + c] = __float2bfloat16(accA[r]);
        HbB[(size_t)(n0 + g * R + r) * M + c] = __float2bfloat16(accB[r]);
    }

    // ---- decision MLP part 2 ----
    __syncthreads();
    if (tid < 32) {
        int node = tid >> 1, o = tid & 1;
        float l = db2[o];
        #pragma unroll 4
        for (int j = 0; j < 64; j++) l += hid[node][j] * dw2[j * 2 + o];
        lg[node][o] = l;
    }
    __syncthreads();
    if (tid < 16) {
        float l0 = lg[tid][0], l1 = lg[tid][1];
        float mm = fmaxf(l0, l1);
        float e0 = __expf(l0 - mm), e1 = __expf(l1 - mm);
        float s = e0 + e1;
        wdec[(size_t)(n0 + tid) * 2 + 0] = e0 / s;
        wdec[(size_t)(n0 + tid) * 2 + 1] = e1 / s;
    }
}

// ---------------- wave-per-node GAT v5: ELL input, single-chunk softmax, BARRIER-FREE ----------------
// deg <= CAP = 64, so one lane per edge; se is wave-private LDS (same-wave RAW needs no barrier).

template <int F, bool HEAD>
__global__ __launch_bounds__(256) void gat5_k(const int* __restrict__ cnt, const int* __restrict__ ell,
                                              const float* __restrict__ elA, const float* __restrict__ erA,
                                              const float* __restrict__ elB, const float* __restrict__ erB,
                                              const unsigned* __restrict__ HuA, const unsigned* __restrict__ HuB,
                                              const float* __restrict__ wdec,
                                              float* __restrict__ outF,
                                              const float* __restrict__ fc1w, const float* __restrict__ fc1b,
                                              const float* __restrict__ fc2w, const float* __restrict__ fc2b,
                                              float* __restrict__ outP, int N) {
    __shared__ uint2 se[4][CAP];                // (src, exBits), wave-private slice
    __shared__ float hs[4][97];                 // head scratch (wave-private)
    const int wid = threadIdx.x >> 6, lane = threadIdx.x & 63;
    const int n = blockIdx.x * 4 + wid;
    const int l5 = lane & 31, sub = lane >> 5;
    float acc0 = 0.f, acc1 = 0.f;

    #pragma unroll
    for (int t = 0; t < 2; t++) {
        int slot = t * N + n;
        int deg = cnt[slot];
        if (deg > CAP) deg = CAP;
        const float* el = t ? elB : elA;
        float ern = (t ? erB : erA)[n];
        const unsigned* Hu = t ? HuB : HuA;
        float coef = wdec[(size_t)n * 2 + t];
        size_t base = (size_t)slot << 6;

        // single-chunk softmax: one edge per lane
        int sv = 0; float ev = -1e30f;
        if (lane < deg) {
            sv = ell[base + lane];
            float e = el[sv] + ern;
            ev = (e > 0.f) ? e : 0.2f * e;
        }
        float mx = ev;
        #pragma unroll
        for (int o = 32; o > 0; o >>= 1) mx = fmaxf(mx, __shfl_xor(mx, o));
        float ex = (lane < deg) ? __expf(ev - mx) : 0.f;
        float sum = ex;
        #pragma unroll
        for (int o = 32; o > 0; o >>= 1) sum += __shfl_xor(sum, o);
        float inv = coef / (sum + 1e-9f);
        se[wid][lane] = make_uint2((unsigned)sv, __float_as_uint(ex));
        // no barrier: wave-private LDS, compiler inserts lgkmcnt wait

        // pipelined gather, uniform LDS broadcast
        float g0 = 0.f, g1 = 0.f;
        if (F == 128) {
            int j = 0;
            for (; j + 4 <= deg; j += 4) {
                uint2 p0 = se[wid][j], p1 = se[wid][j + 1], p2 = se[wid][j + 2], p3 = se[wid][j + 3];
                unsigned h0 = Hu[(size_t)p0.x * 64 + lane];
                unsigned h1 = Hu[(size_t)p1.x * 64 + lane];
                unsigned h2 = Hu[(size_t)p2.x * 64 + lane];
                unsigned h3 = Hu[(size_t)p3.x * 64 + lane];
                float w0 = __uint_as_float(p0.y), w1 = __uint_as_float(p1.y);
                float w2 = __uint_as_float(p2.y), w3 = __uint_as_float(p3.y);
                g0 = fmaf(w0, __uint_as_float(h0 << 16), g0);
                g1 = fmaf(w0, __uint_as_float(h0 & 0xffff0000u), g1);
                g0 = fmaf(w1, __uint_as_float(h1 << 16), g0);
                g1 = fmaf(w1, __uint_as_float(h1 & 0xffff0000u), g1);
                g0 = fmaf(w2, __uint_as_float(h2 << 16), g0);
                g1 = fmaf(w2, __uint_as_float(h2 & 0xffff0000u), g1);
                g0 = fmaf(w3, __uint_as_float(h3 << 16), g0);
                g1 = fmaf(w3, __uint_as_float(h3 & 0xffff0000u), g1);
            }
            for (; j < deg; j++) {
                uint2 p = se[wid][j];
                unsigned h = Hu[(size_t)p.x * 64 + lane];
                float w = __uint_as_float(p.y);
                g0 = fmaf(w, __uint_as_float(h << 16), g0);
                g1 = fmaf(w, __uint_as_float(h & 0xffff0000u), g1);
            }
        } else {
            // half-wave per edge: sub 0 -> even edges, sub 1 -> odd edges
            int j = sub;
            for (; j + 7 <= deg; j += 8) {
                uint2 p0 = se[wid][j], p1 = se[wid][j + 2], p2 = se[wid][j + 4], p3 = se[wid][j + 6];
                unsigned h0 = Hu[(size_t)p0.x * 32 + l5];
                unsigned h1 = Hu[(size_t)p1.x * 32 + l5];
                unsigned h2 = Hu[(size_t)p2.x * 32 + l5];
                unsigned h3 = Hu[(size_t)p3.x * 32 + l5];
                float w0 = __uint_as_float(p0.y), w1 = __uint_as_float(p1.y);
                float w2 = __uint_as_float(p2.y), w3 = __uint_as_float(p3.y);
                g0 = fmaf(w0, __uint_as_float(h0 << 16), g0);
                g1 = fmaf(w0, __uint_as_float(h0 & 0xffff0000u), g1);
                g0 = fmaf(w1, __uint_as_float(h1 << 16), g0);
                g1 = fmaf(w1, __uint_as_float(h1 & 0xffff0000u), g1);
                g0 = fmaf(w2, __uint_as_float(h2 << 16), g0);
                g1 = fmaf(w2, __uint_as_float(h2 & 0xffff0000u), g1);
                g0 = fmaf(w3, __uint_as_float(h3 << 16), g0);
                g1 = fmaf(w3, __uint_as_float(h3 & 0xffff0000u), g1);
            }
            for (; j < deg; j += 2) {
                uint2 p = se[wid][j];
                unsigned h = Hu[(size_t)p.x * 32 + l5];
                float w = __uint_as_float(p.y);
                g0 = fmaf(w, __uint_as_float(h << 16), g0);
                g1 = fmaf(w, __uint_as_float(h & 0xffff0000u), g1);
            }
        }
        acc0 = fmaf(inv, g0, acc0);
        acc1 = fmaf(inv, g1, acc1);
    }

    if (F == 64) {                              // combine the two half-wave edge partitions
        acc0 += __shfl_xor(acc0, 32);
        acc1 += __shfl_xor(acc1, 32);
    }

    if (!HEAD) {
        float2 v;
        v.x = fmaxf(acc0, 0.f);
        v.y = fmaxf(acc1, 0.f);
        ((float2*)outF)[(size_t)n * (F / 2) + lane] = v;
    } else {
        // relu -> 64->32 relu -> 2 -> softmax, wave-local (hs wave-private: no barrier)
        if (lane < 32) {
            hs[wid][2 * l5 + 0] = fmaxf(acc0, 0.f);
            hs[wid][2 * l5 + 1] = fmaxf(acc1, 0.f);
        }
        if (lane < 32) {
            float h1 = fc1b[lane];
            #pragma unroll 4
            for (int k = 0; k < 64; k++) h1 += hs[wid][k] * fc1w[k * 32 + lane];
            hs[wid][64 + lane] = fmaxf(h1, 0.f);
        }
        if (lane < 2) {
            float l = fc2b[lane];
            #pragma unroll 4
            for (int j = 0; j < 32; j++) l += hs[wid][64 + j] * fc2w[j * 2 + lane];
            float lo = __shfl(l, 0), lhi = __shfl(l, 1);
            if (lane == 0) {
                float mm = fmaxf(lo, lhi);
                float e0 = __expf(lo - mm), e1 = __expf(lhi - mm);
                float s = e0 + e1;
                float2 pr; pr.x = e0 / s; pr.y = e1 / s;
                ((float2*)outP)[n] = pr;
            }
        }
    }
}

// ---------------- launch ----------------

extern "C" void kernel_launch(void* const* d_in, const int* in_sizes, int n_in,
                              void* d_out, int out_size, void* d_ws, size_t ws_size,
                              hipStream_t stream) {
    const float* x     = (const float*)d_in[0];
    const int*   eiA   = (const int*)d_in[1];
    const int*   eiB   = (const int*)d_in[2];
    const float* W1    = (const float*)d_in[3];
    const float* a1    = (const float*)d_in[4];
    const float* d1w1  = (const float*)d_in[5];
    const float* d1b1  = (const float*)d_in[6];
    const float* d1w2  = (const float*)d_in[7];
    const float* d1b2  = (const float*)d_in[8];
    const float* W2    = (const float*)d_in[9];
    const float* a2    = (const float*)d_in[10];
    const float* d2w1  = (const float*)d_in[11];
    const float* d2b1  = (const float*)d_in[12];
    const float* d2w2  = (const float*)d_in[13];
    const float* d2b2  = (const float*)d_in[14];
    const float* fc1w  = (const float*)d_in[15];
    const float* fc1b  = (const float*)d_in[16];
    const float* fc2w  = (const float*)d_in[17];
    const float* fc2b  = (const float*)d_in[18];
    float* out = (float*)d_out;

    const int N = NN;

    char* ws = (char*)d_ws;
    size_t off = 0;
    auto alloc = [&](size_t bytes) -> char* {
        char* p = ws + off;
        off = (off + bytes + 255) & ~(size_t)255;
        return p;
    };
    int*   cntAll = (int*)alloc((size_t)2 * N * sizeof(int));
    int*   ell    = (int*)alloc((size_t)2 * N * CAP * sizeof(int));
    float* wa     = (float*)alloc(8 * 128 * sizeof(float));
    float* wdec   = (float*)alloc((size_t)N * 2 * sizeof(float));
    float* elA    = (float*)alloc(N * sizeof(float));
    float* erA    = (float*)alloc(N * sizeof(float));
    float* elB    = (float*)alloc(N * sizeof(float));
    float* erB    = (float*)alloc(N * sizeof(float));
    __hip_bfloat16* HbA = (__hip_bfloat16*)alloc((size_t)N * 128 * sizeof(__hip_bfloat16));
    __hip_bfloat16* HbB = (__hip_bfloat16*)alloc((size_t)N * 128 * sizeof(__hip_bfloat16));
    float* hOut1  = (float*)alloc((size_t)N * 128 * sizeof(float));

    // ---- cnt zero + wa precompute ----
    hipMemsetAsync(cntAll, 0, (size_t)2 * N * sizeof(int), stream);
    wa_k<<<4, 256, 0, stream>>>(W1, a1, W2, a2, wa);

    // ---- Layer 1 (+ ELL build latency-split under the GEMM) ----
    fusedgemm_k<128, true><<<N / 16, 256, 0, stream>>>(x, W1, W1 + 128 * 128, wa,
                                                       d1w1, d1b1, d1w2, d1b2,
                                                       HbA, HbB, elA, erA, elB, erB, wdec,
                                                       eiA, eiB, cntAll, ell);
    gat5_k<128, false><<<N / 4, 256, 0, stream>>>(cntAll, ell, elA, erA, elB, erB,
                                                  (const unsigned*)HbA, (const unsigned*)HbB,
                                                  wdec, hOut1,
                                                  nullptr, nullptr, nullptr, nullptr, nullptr, N);

    // ---- Layer 2 (head fused) ----
    fusedgemm_k<64, false><<<N / 16, 256, 0, stream>>>(hOut1, W2, W2 + 128 * 64, wa + 512,
                                                       d2w1, d2b1, d2w2, d2b2,
                                                       HbA, HbB, elA, erA, elB, erB, wdec,
                                                       nullptr, nullptr, nullptr, nullptr);
    gat5_k<64, true><<<N / 4, 256, 0, stream>>>(cntAll, ell, elA, erA, elB, erB,
                                                (const unsigned*)HbA, (const unsigned*)HbB,
                                                wdec, nullptr,
                                                fc1w, fc1b, fc2w, fc2b, out, N);
}

// Round 13
// 361.080 us; speedup vs baseline: 3.4710x; 3.4710x over previous
//
#include <hip/hip_runtime.h>
#include <hip/hip_bf16.h>

#define NN   40000
#define EE   640000
#define CAP  64        // ELL slots per (node, edge-type); P(Poisson(16) > 64) ~ 1e-19

// ---------------- tiny precompute: wa[v][k] = (W @ a_vec)[k], 8 vectors of length 128 ----------------
// Valid because el = (X@W)@a0 = X@(W@a0); K=128 for both layers.

__global__ __launch_bounds__(256) void wa_k(const float* __restrict__ W1, const float* __restrict__ a1,
                                            const float* __restrict__ W2, const float* __restrict__ a2,
                                            float* __restrict__ wa) {
    int gid = blockIdx.x * 256 + threadIdx.x;    // 0..1023
    int v = gid >> 7, k = gid & 127;
    float s = 0.f;
    if (v < 4) {
        const float* W = W1 + (v >> 1) * 128 * 128;
        const float* a = a1 + (v >> 1) * 2 * 128 + (v & 1) * 128;
        #pragma unroll 4
        for (int c = 0; c < 128; c++) s += W[k * 128 + c] * a[c];
    } else {
        int u = v - 4;
        const float* W = W2 + (u >> 1) * 128 * 64;
        const float* a = a2 + (u >> 1) * 2 * 64 + (u & 1) * 64;
        #pragma unroll 4
        for (int c = 0; c < 64; c++) s += W[k * 64 + c] * a[c];
    }
    wa[gid] = s;
}

// ---------------- fused: GEMM (both types, bf16 out) + el/er via wa + decision MLP
//                  + (layer 1 only) ELL build — monolithic pre-barrier (round-7 codegen, no spill).
// NOTE: do NOT split the BUILD chain across compute phases and do NOT add a min-waves
// launch bound: both variants spilled catastrophically (rounds 11/12: VGPR 256 / scratch 2.7GB).

template <int M, bool BUILD>
__global__ __launch_bounds__(256) void fusedgemm_k(const float* __restrict__ X,
                                                   const float* __restrict__ WA, const float* __restrict__ WB,
                                                   const float* __restrict__ wa,   // 4 vectors x 128 (layer-selected)
                                                   const float* __restrict__ dw1, const float* __restrict__ db1,
                                                   const float* __restrict__ dw2, const float* __restrict__ db2,
                                                   __hip_bfloat16* __restrict__ HbA, __hip_bfloat16* __restrict__ HbB,
                                                   float* __restrict__ elA, float* __restrict__ erA,
                                                   float* __restrict__ elB, float* __restrict__ erB,
                                                   float* __restrict__ wdec,
                                                   const int* __restrict__ eiA, const int* __restrict__ eiB,
                                                   int* __restrict__ cnt, int* __restrict__ ell) {
    constexpr int K = 128;
    constexpr int NB = 16;
    constexpr int G = 256 / M;   // 2 (M=128) or 4 (M=64)
    constexpr int R = NB / G;    // 8 or 4
    __shared__ float xs[NB][K + 4];   // row stride 132 floats = 528B, 16B-aligned
    __shared__ float hid[NB][65];
    __shared__ float lg[16][2];
    int n0 = blockIdx.x * NB;
    int tid = threadIdx.x;

    // ---- BUILD: issue edge loads first (latency overlaps X staging below) ----
    int sA, dA, sB, dB;
    if (BUILD) {
        int gid = blockIdx.x * 256 + tid;          // grid is exactly 640000 = E threads
        sA = eiA[gid]; dA = eiA[EE + gid];
        sB = eiB[gid]; dB = NN + eiB[EE + gid];
    }

    // ---- stage X tile (float4) ----
    for (int idx = tid; idx < NB * (K / 4); idx += 256) {
        int r = idx >> 5, k4 = (idx & 31) << 2;
        *(float4*)&xs[r][k4] = *(const float4*)&X[(size_t)(n0 + r) * K + k4];
    }

    // ---- BUILD: atomic + store, completed before the barrier (nothing lives across it) ----
    if (BUILD) {
        int cA = atomicAdd(&cnt[dA], 1);
        if (cA < CAP) ell[((size_t)dA << 6) + cA] = sA;
        int cB = atomicAdd(&cnt[dB], 1);
        if (cB < CAP) ell[((size_t)dB << 6) + cB] = sB;
    }
    __syncthreads();

    // ---- GEMM both types: float4 xs broadcasts ----
    const int c = tid % M;
    const int g = tid / M;
    float accA[R], accB[R];
    #pragma unroll
    for (int r = 0; r < R; r++) { accA[r] = 0.f; accB[r] = 0.f; }
    for (int k4 = 0; k4 < K; k4 += 4) {
        float4 xv[R];
        #pragma unroll
        for (int r = 0; r < R; r++) xv[r] = *(float4*)&xs[g * R + r][k4];
        #define GSTEP(comp, kk)                                              \
        {                                                                    \
            float wA = WA[(k4 + kk) * M + c];                                \
            float wB = WB[(k4 + kk) * M + c];                                \
            _Pragma("unroll")                                                \
            for (int r = 0; r < R; r++) {                                    \
                accA[r] = fmaf(xv[r].comp, wA, accA[r]);                     \
                accB[r] = fmaf(xv[r].comp, wB, accB[r]);                     \
            }                                                                \
        }
        GSTEP(x, 0) GSTEP(y, 1) GSTEP(z, 2) GSTEP(w, 3)
        #undef GSTEP
    }

    // ---- bf16 H stores ----
    #pragma unroll
    for (int r = 0; r < R; r++) {
        HbA[(size_t)(n0 + g * R + r) * M + c] = __float2bfloat16(accA[r]);
        HbB[(size_t)(n0 + g * R + r) * M + c] = __float2bfloat16(accB[r]);
    }

    // ---- el/er from precomputed wa vectors: barrier-free row-dot over xs ----
    {
        int row = tid >> 4, lane16 = tid & 15;
        float s0 = 0.f, s1 = 0.f, s2 = 0.f, s3 = 0.f;
        #pragma unroll
        for (int kk = 0; kk < 8; kk++) {
            int k = lane16 + kk * 16;
            float xv = xs[row][k];
            s0 = fmaf(xv, wa[0 * 128 + k], s0);
            s1 = fmaf(xv, wa[1 * 128 + k], s1);
            s2 = fmaf(xv, wa[2 * 128 + k], s2);
            s3 = fmaf(xv, wa[3 * 128 + k], s3);
        }
        #pragma unroll
        for (int o = 8; o > 0; o >>= 1) {
            s0 += __shfl_down(s0, o, 16);
            s1 += __shfl_down(s1, o, 16);
            s2 += __shfl_down(s2, o, 16);
            s3 += __shfl_down(s3, o, 16);
        }
        if (lane16 == 0) {
            elA[n0 + row] = s0; erA[n0 + row] = s1;
            elB[n0 + row] = s2; erB[n0 + row] = s3;
        }
    }

    // ---- decision MLP part 1: float4 xs reads ----
    {
        int dc = tid & 63, dg = tid >> 6;      // 4 groups x 4 rows
        float da[4] = {0.f, 0.f, 0.f, 0.f};
        for (int k4 = 0; k4 < 128; k4 += 4) {
            float4 xr[4];
            #pragma unroll
            for (int r = 0; r < 4; r++) xr[r] = *(float4*)&xs[dg * 4 + r][k4];
            float w0 = dw1[(k4 + 0) * 64 + dc];
            float w1 = dw1[(k4 + 1) * 64 + dc];
            float w2 = dw1[(k4 + 2) * 64 + dc];
            float w3 = dw1[(k4 + 3) * 64 + dc];
            #pragma unroll
            for (int r = 0; r < 4; r++) {
                float s = fmaf(xr[r].x, w0, fmaf(xr[r].y, w1, fmaf(xr[r].z, w2, xr[r].w * w3)));
                da[r] += s;
            }
        }
        float b = db1[dc];
        #pragma unroll
        for (int r = 0; r < 4; r++) hid[dg * 4 + r][dc] = fmaxf(da[r] + b, 0.f);
    }
    __syncthreads();
    if (tid < 32) {
        int node = tid >> 1, o = tid & 1;
        float l = db2[o];
        #pragma unroll 4
        for (int j = 0; j < 64; j++) l += hid[node][j] * dw2[j * 2 + o];
        lg[node][o] = l;
    }
    __syncthreads();
    if (tid < 16) {
        float l0 = lg[tid][0], l1 = lg[tid][1];
        float mm = fmaxf(l0, l1);
        float e0 = __expf(l0 - mm), e1 = __expf(l1 - mm);
        float s = e0 + e1;
        wdec[(size_t)(n0 + tid) * 2 + 0] = e0 / s;
        wdec[(size_t)(n0 + tid) * 2 + 1] = e1 / s;
    }
}

// ---------------- wave-per-node GAT v5: ELL input, single-chunk softmax, BARRIER-FREE ----------------
// deg <= CAP = 64, so one lane per edge; se is wave-private LDS (same-wave RAW needs no barrier).

template <int F, bool HEAD>
__global__ __launch_bounds__(256) void gat5_k(const int* __restrict__ cnt, const int* __restrict__ ell,
                                              const float* __restrict__ elA, const float* __restrict__ erA,
                                              const float* __restrict__ elB, const float* __restrict__ erB,
                                              const unsigned* __restrict__ HuA, const unsigned* __restrict__ HuB,
                                              const float* __restrict__ wdec,
                                              float* __restrict__ outF,
                                              const float* __restrict__ fc1w, const float* __restrict__ fc1b,
                                              const float* __restrict__ fc2w, const float* __restrict__ fc2b,
                                              float* __restrict__ outP, int N) {
    __shared__ uint2 se[4][CAP];                // (src, exBits), wave-private slice
    __shared__ float hs[4][97];                 // head scratch (wave-private)
    const int wid = threadIdx.x >> 6, lane = threadIdx.x & 63;
    const int n = blockIdx.x * 4 + wid;
    const int l5 = lane & 31, sub = lane >> 5;
    float acc0 = 0.f, acc1 = 0.f;

    #pragma unroll
    for (int t = 0; t < 2; t++) {
        int slot = t * N + n;
        int deg = cnt[slot];
        if (deg > CAP) deg = CAP;
        const float* el = t ? elB : elA;
        float ern = (t ? erB : erA)[n];
        const unsigned* Hu = t ? HuB : HuA;
        float coef = wdec[(size_t)n * 2 + t];
        size_t base = (size_t)slot << 6;

        // single-chunk softmax: one edge per lane
        int sv = 0; float ev = -1e30f;
        if (lane < deg) {
            sv = ell[base + lane];
            float e = el[sv] + ern;
            ev = (e > 0.f) ? e : 0.2f * e;
        }
        float mx = ev;
        #pragma unroll
        for (int o = 32; o > 0; o >>= 1) mx = fmaxf(mx, __shfl_xor(mx, o));
        float ex = (lane < deg) ? __expf(ev - mx) : 0.f;
        float sum = ex;
        #pragma unroll
        for (int o = 32; o > 0; o >>= 1) sum += __shfl_xor(sum, o);
        float inv = coef / (sum + 1e-9f);
        se[wid][lane] = make_uint2((unsigned)sv, __float_as_uint(ex));
        // no barrier: wave-private LDS, compiler inserts lgkmcnt wait

        // pipelined gather, uniform LDS broadcast
        float g0 = 0.f, g1 = 0.f;
        if (F == 128) {
            int j = 0;
            for (; j + 4 <= deg; j += 4) {
                uint2 p0 = se[wid][j], p1 = se[wid][j + 1], p2 = se[wid][j + 2], p3 = se[wid][j + 3];
                unsigned h0 = Hu[(size_t)p0.x * 64 + lane];
                unsigned h1 = Hu[(size_t)p1.x * 64 + lane];
                unsigned h2 = Hu[(size_t)p2.x * 64 + lane];
                unsigned h3 = Hu[(size_t)p3.x * 64 + lane];
                float w0 = __uint_as_float(p0.y), w1 = __uint_as_float(p1.y);
                float w2 = __uint_as_float(p2.y), w3 = __uint_as_float(p3.y);
                g0 = fmaf(w0, __uint_as_float(h0 << 16), g0);
                g1 = fmaf(w0, __uint_as_float(h0 & 0xffff0000u), g1);
                g0 = fmaf(w1, __uint_as_float(h1 << 16), g0);
                g1 = fmaf(w1, __uint_as_float(h1 & 0xffff0000u), g1);
                g0 = fmaf(w2, __uint_as_float(h2 << 16), g0);
                g1 = fmaf(w2, __uint_as_float(h2 & 0xffff0000u), g1);
                g0 = fmaf(w3, __uint_as_float(h3 << 16), g0);
                g1 = fmaf(w3, __uint_as_float(h3 & 0xffff0000u), g1);
            }
            for (; j < deg; j++) {
                uint2 p = se[wid][j];
                unsigned h = Hu[(size_t)p.x * 64 + lane];
                float w = __uint_as_float(p.y);
                g0 = fmaf(w, __uint_as_float(h << 16), g0);
                g1 = fmaf(w, __uint_as_float(h & 0xffff0000u), g1);
            }
        } else {
            // half-wave per edge: sub 0 -> even edges, sub 1 -> odd edges
            int j = sub;
            for (; j + 7 <= deg; j += 8) {
                uint2 p0 = se[wid][j], p1 = se[wid][j + 2], p2 = se[wid][j + 4], p3 = se[wid][j + 6];
                unsigned h0 = Hu[(size_t)p0.x * 32 + l5];
                unsigned h1 = Hu[(size_t)p1.x * 32 + l5];
                unsigned h2 = Hu[(size_t)p2.x * 32 + l5];
                unsigned h3 = Hu[(size_t)p3.x * 32 + l5];
                float w0 = __uint_as_float(p0.y), w1 = __uint_as_float(p1.y);
                float w2 = __uint_as_float(p2.y), w3 = __uint_as_float(p3.y);
                g0 = fmaf(w0, __uint_as_float(h0 << 16), g0);
                g1 = fmaf(w0, __uint_as_float(h0 & 0xffff0000u), g1);
                g0 = fmaf(w1, __uint_as_float(h1 << 16), g0);
                g1 = fmaf(w1, __uint_as_float(h1 & 0xffff0000u), g1);
                g0 = fmaf(w2, __uint_as_float(h2 << 16), g0);
                g1 = fmaf(w2, __uint_as_float(h2 & 0xffff0000u), g1);
                g0 = fmaf(w3, __uint_as_float(h3 << 16), g0);
                g1 = fmaf(w3, __uint_as_float(h3 & 0xffff0000u), g1);
            }
            for (; j < deg; j += 2) {
                uint2 p = se[wid][j];
                unsigned h = Hu[(size_t)p.x * 32 + l5];
                float w = __uint_as_float(p.y);
                g0 = fmaf(w, __uint_as_float(h << 16), g0);
                g1 = fmaf(w, __uint_as_float(h & 0xffff0000u), g1);
            }
        }
        acc0 = fmaf(inv, g0, acc0);
        acc1 = fmaf(inv, g1, acc1);
    }

    if (F == 64) {                              // combine the two half-wave edge partitions
        acc0 += __shfl_xor(acc0, 32);
        acc1 += __shfl_xor(acc1, 32);
    }

    if (!HEAD) {
        float2 v;
        v.x = fmaxf(acc0, 0.f);
        v.y = fmaxf(acc1, 0.f);
        ((float2*)outF)[(size_t)n * (F / 2) + lane] = v;
    } else {
        // relu -> 64->32 relu -> 2 -> softmax, wave-local (hs wave-private: no barrier)
        if (lane < 32) {
            hs[wid][2 * l5 + 0] = fmaxf(acc0, 0.f);
            hs[wid][2 * l5 + 1] = fmaxf(acc1, 0.f);
        }
        if (lane < 32) {
            float h1 = fc1b[lane];
            #pragma unroll 4
            for (int k = 0; k < 64; k++) h1 += hs[wid][k] * fc1w[k * 32 + lane];
            hs[wid][64 + lane] = fmaxf(h1, 0.f);
        }
        if (lane < 2) {
            float l = fc2b[lane];
            #pragma unroll 4
            for (int j = 0; j < 32; j++) l += hs[wid][64 + j] * fc2w[j * 2 + lane];
            float lo = __shfl(l, 0), lhi = __shfl(l, 1);
            if (lane == 0) {
                float mm = fmaxf(lo, lhi);
                float e0 = __expf(lo - mm), e1 = __expf(lhi - mm);
                float s = e0 + e1;
                float2 pr; pr.x = e0 / s; pr.y = e1 / s;
                ((float2*)outP)[n] = pr;
            }
        }
    }
}

// ---------------- launch ----------------

extern "C" void kernel_launch(void* const* d_in, const int* in_sizes, int n_in,
                              void* d_out, int out_size, void* d_ws, size_t ws_size,
                              hipStream_t stream) {
    const float* x     = (const float*)d_in[0];
    const int*   eiA   = (const int*)d_in[1];
    const int*   eiB   = (const int*)d_in[2];
    const float* W1    = (const float*)d_in[3];
    const float* a1    = (const float*)d_in[4];
    const float* d1w1  = (const float*)d_in[5];
    const float* d1b1  = (const float*)d_in[6];
    const float* d1w2  = (const float*)d_in[7];
    const float* d1b2  = (const float*)d_in[8];
    const float* W2    = (const float*)d_in[9];
    const float* a2    = (const float*)d_in[10];
    const float* d2w1  = (const float*)d_in[11];
    const float* d2b1  = (const float*)d_in[12];
    const float* d2w2  = (const float*)d_in[13];
    const float* d2b2  = (const float*)d_in[14];
    const float* fc1w  = (const float*)d_in[15];
    const float* fc1b  = (const float*)d_in[16];
    const float* fc2w  = (const float*)d_in[17];
    const float* fc2b  = (const float*)d_in[18];
    float* out = (float*)d_out;

    const int N = NN;

    char* ws = (char*)d_ws;
    size_t off = 0;
    auto alloc = [&](size_t bytes) -> char* {
        char* p = ws + off;
        off = (off + bytes + 255) & ~(size_t)255;
        return p;
    };
    int*   cntAll = (int*)alloc((size_t)2 * N * sizeof(int));
    int*   ell    = (int*)alloc((size_t)2 * N * CAP * sizeof(int));
    float* wa     = (float*)alloc(8 * 128 * sizeof(float));
    float* wdec   = (float*)alloc((size_t)N * 2 * sizeof(float));
    float* elA    = (float*)alloc(N * sizeof(float));
    float* erA    = (float*)alloc(N * sizeof(float));
    float* elB    = (float*)alloc(N * sizeof(float));
    float* erB    = (float*)alloc(N * sizeof(float));
    __hip_bfloat16* HbA = (__hip_bfloat16*)alloc((size_t)N * 128 * sizeof(__hip_bfloat16));
    __hip_bfloat16* HbB = (__hip_bfloat16*)alloc((size_t)N * 128 * sizeof(__hip_bfloat16));
    float* hOut1  = (float*)alloc((size_t)N * 128 * sizeof(float));

    // ---- cnt zero + wa precompute ----
    hipMemsetAsync(cntAll, 0, (size_t)2 * N * sizeof(int), stream);
    wa_k<<<4, 256, 0, stream>>>(W1, a1, W2, a2, wa);

    // ---- Layer 1 (+ ELL build fused, pre-barrier) ----
    fusedgemm_k<128, true><<<N / 16, 256, 0, stream>>>(x, W1, W1 + 128 * 128, wa,
                                                       d1w1, d1b1, d1w2, d1b2,
                                                       HbA, HbB, elA, erA, elB, erB, wdec,
                                                       eiA, eiB, cntAll, ell);
    gat5_k<128, false><<<N / 4, 256, 0, stream>>>(cntAll, ell, elA, erA, elB, erB,
                                                  (const unsigned*)HbA, (const unsigned*)HbB,
                                                  wdec, hOut1,
                                                  nullptr, nullptr, nullptr, nullptr, nullptr, N);

    // ---- Layer 2 (head fused) ----
    fusedgemm_k<64, false><<<N / 16, 256, 0, stream>>>(hOut1, W2, W2 + 128 * 64, wa + 512,
                                                       d2w1, d2b1, d2w2, d2b2,
                                                       HbA, HbB, elA, erA, elB, erB, wdec,
                                                       nullptr, nullptr, nullptr, nullptr);
    gat5_k<64, true><<<N / 4, 256, 0, stream>>>(cntAll, ell, elA, erA, elB, erB,
                                                (const unsigned*)HbA, (const unsigned*)HbB,
                                                wdec, nullptr,
                                                fc1w, fc1b, fc2w, fc2b, out, N);
}